// Round 9
// baseline (819.364 us; speedup 1.0000x reference)
//
#include <hip/hip_runtime.h>
#include <cmath>

// SimplicialAttentionLayer: out = softmax((H Wq)(H Wk)^T * A / sqrt(D)) @ (H Wv)
// N=8192, D=512, fp32.
//  gemm_bt: fused 3-projection GEMM -> HQ/HK/HV hi/lo bf16 (proven 128x128)
//  k_quant: HQ/HK -> per-row-scaled int16 split into hi8/lo8 planes + sQ/sK
//  k_iscore: scores via i8 MFMA (16x16x64), 3 passes into 2 i32 accs
//            (S = sq*sk*(65536*hh + 256*mid)); R3-proven 2-barrier skeleton,
//            128(kv)x64(q) tile, packed hi|lo 128-B LDS rows, slot-XOR swizzle.
//            Epilogue: mask*scale, 128-kv chunk softmax, P' bf16, mC/lC.
//  k_reduce: F[c][q] = exp(m_c - m_fin)/L
//  k_big<3,1,4>: PV 1-pass bf16, F folded into staging, K-split 4-way
//  k_sumout3: fold partials

typedef unsigned short u16;
typedef unsigned int   u32;
typedef float f32x4 __attribute__((ext_vector_type(4)));
typedef short s16x8 __attribute__((ext_vector_type(8)));
typedef int   i32x4 __attribute__((ext_vector_type(4)));

#define DEVI static __device__ __forceinline__

DEVI u16 f2bf(float x) { u32 u = __float_as_uint(x); u32 r = u + 0x7fffu + ((u >> 16) & 1u); return (u16)(r >> 16); }
DEVI float bf2f(u16 b) { return __uint_as_float((u32)b << 16); }

DEVI f32x4 mm_bf16(s16x8 a, s16x8 b, f32x4 c) {
  return __builtin_amdgcn_mfma_f32_16x16x32_bf16(a, b, c, 0, 0, 0);
}
DEVI i32x4 mm_i8(i32x4 a, i32x4 b, i32x4 c) {
  return __builtin_amdgcn_mfma_i32_16x16x64_i8(a, b, c, 0, 0, 0);
}

// scale 8 packed bf16 by f, round-nearest, repack via v_perm
DEVI uint4 scaleP(uint4 v, float f) {
  u32* w = (u32*)&v;
#pragma unroll
  for (int j = 0; j < 4; j++) {
    u32 lo = __float_as_uint(__uint_as_float(w[j] << 16) * f) + 0x8000u;
    u32 hi = __float_as_uint(__uint_as_float(w[j] & 0xffff0000u) * f) + 0x8000u;
    w[j] = __builtin_amdgcn_perm(hi, lo, 0x07060302);
  }
  return v;
}

// ---------------- elementwise prep kernels ----------------

__global__ void k_split(const float* __restrict__ X, u16* __restrict__ Xhi, u16* __restrict__ Xlo, int n4) {
  int i = blockIdx.x * 256 + threadIdx.x;
  if (i >= n4) return;
  float4 v = ((const float4*)X)[i];
  u16 h0 = f2bf(v.x), h1 = f2bf(v.y), h2 = f2bf(v.z), h3 = f2bf(v.w);
  u16 l0 = f2bf(v.x - bf2f(h0)), l1 = f2bf(v.y - bf2f(h1));
  u16 l2 = f2bf(v.z - bf2f(h2)), l3 = f2bf(v.w - bf2f(h3));
  ((uint2*)Xhi)[i] = make_uint2((u32)h0 | ((u32)h1 << 16), (u32)h2 | ((u32)h3 << 16));
  ((uint2*)Xlo)[i] = make_uint2((u32)l0 | ((u32)l1 << 16), (u32)l2 | ((u32)l3 << 16));
}

__global__ void k_prepW(const float* __restrict__ W0, const float* __restrict__ W1, const float* __restrict__ W2,
                        u16* __restrict__ Thi, u16* __restrict__ Tlo) {
  int idx = blockIdx.x * 256 + threadIdx.x;
  if (idx >= 3 * 512 * 512) return;
  int w = idx >> 18, n = (idx >> 9) & 511, k = idx & 511;
  const float* W = (w == 0) ? W0 : (w == 1) ? W1 : W2;
  float v = W[k * 512 + n];
  u16 h = f2bf(v);
  Thi[idx] = h;
  Tlo[idx] = f2bf(v - bf2f(h));
}

__global__ void k_transpose(const u16* __restrict__ in, u16* __restrict__ out, int R, int C) {
  __shared__ u16 t[64][72];
  const int rb = blockIdx.x * 64, cb = blockIdx.y * 64;
  const int r = threadIdx.x >> 2, c4 = (threadIdx.x & 3) * 16;
  const u16* src = in + (size_t)(rb + r) * C + cb + c4;
  *(uint4*)&t[r][c4] = *(const uint4*)src;
  *(uint4*)&t[r][c4 + 8] = *(const uint4*)(src + 8);
  __syncthreads();
  u16 v[16];
#pragma unroll
  for (int j = 0; j < 16; j++) v[j] = t[c4 + j][r];
  uint4 o0, o1;
  o0.x = v[0] | ((u32)v[1] << 16); o0.y = v[2] | ((u32)v[3] << 16);
  o0.z = v[4] | ((u32)v[5] << 16); o0.w = v[6] | ((u32)v[7] << 16);
  o1.x = v[8] | ((u32)v[9] << 16); o1.y = v[10] | ((u32)v[11] << 16);
  o1.z = v[12] | ((u32)v[13] << 16); o1.w = v[14] | ((u32)v[15] << 16);
  u16* dst = out + (size_t)(cb + r) * R + rb + c4;
  *(uint4*)dst = o0;
  *(uint4*)(dst + 8) = o1;
}

// ---------------- int16 row-quantization: x ~ s*(256*h8 + l8) ----------------
// one wave per row; s = rowmax/32512 so |v|<=32512, h8 in [-127,127], l8 in [-128,127]

__global__ void k_quant(const u16* __restrict__ hi, const u16* __restrict__ lo,
                        char* __restrict__ q8h, char* __restrict__ q8l, float* __restrict__ sc) {
  const int row = blockIdx.x * 4 + (threadIdx.x >> 6);
  const int lane = threadIdx.x & 63;
  const size_t base = (size_t)row * 512 + lane * 8;
  uint4 vh = *(const uint4*)(hi + base);
  uint4 vl = *(const uint4*)(lo + base);
  const u32* ph = (const u32*)&vh;
  const u32* pl = (const u32*)&vl;
  float x[8];
#pragma unroll
  for (int j = 0; j < 4; j++) {
    x[2 * j]     = bf2f((u16)(ph[j] & 0xffff)) + bf2f((u16)(pl[j] & 0xffff));
    x[2 * j + 1] = bf2f((u16)(ph[j] >> 16))    + bf2f((u16)(pl[j] >> 16));
  }
  float amax = 0.f;
#pragma unroll
  for (int j = 0; j < 8; j++) amax = fmaxf(amax, fabsf(x[j]));
#pragma unroll
  for (int d = 1; d < 64; d <<= 1) amax = fmaxf(amax, __shfl_xor(amax, d));
  amax = fmaxf(amax, 1e-30f);
  const float s = amax * (1.0f / 32512.f);
  const float inv = 32512.f / amax;
  u32 hb0 = 0, hb1 = 0, lb0 = 0, lb1 = 0;
#pragma unroll
  for (int j = 0; j < 8; j++) {
    int v = (int)rintf(x[j] * inv);
    int h = (v + 128) >> 8;
    int l = v - (h << 8);
    if (j < 4) { hb0 |= (u32)(h & 255) << (j * 8);       lb0 |= (u32)(l & 255) << (j * 8); }
    else       { hb1 |= (u32)(h & 255) << ((j - 4) * 8); lb1 |= (u32)(l & 255) << ((j - 4) * 8); }
  }
  *(uint2*)(q8h + base) = make_uint2(hb0, hb1);
  *(uint2*)(q8l + base) = make_uint2(lb0, lb1);
  if (lane == 0) sc[row] = s;
}

// ---------------- k_iscore: i8 scores, 128(kv) x 64(q) tile, 4 waves ----------------
// LDS: A-region [128 rows][128 B] (8x16B units: u<4 = hi chunk u, u>=4 = lo chunk u-4,
// phys slot p = u ^ (row&7)); B-region [64 rows][128 B] at +16384. 2-barrier skeleton.

__launch_bounds__(256, 4)
__global__ void k_iscore(const char* __restrict__ Kh8, const char* __restrict__ Kl8,
                         const char* __restrict__ Qh8, const char* __restrict__ Ql8,
                         const float* __restrict__ sK, const float* __restrict__ sQ,
                         const float* __restrict__ Adj, float* __restrict__ mC,
                         float* __restrict__ lC, u16* __restrict__ Pout, float scale)
{
  constexpr int NN = 8192;
  __shared__ __align__(16) char lds[24576];

  const int tid = threadIdx.x, lane = tid & 63, wid = tid >> 6;
  const int wm = wid >> 1, wn = wid & 1;   // wave: kv [wm*64,+64) x q [wn*32,+32)
  const int lr = lane & 15, lk = lane >> 4;
  const int mbase = blockIdx.x * 128, nbase = blockIdx.y * 64;

  // staging: round j dest byte = tid*16 + j*4096; logical unit is j-invariant
  const int su = (tid & 7) ^ ((tid >> 3) & 7);
  const char* aPlane = (su < 4) ? Kh8 : Kl8;
  const char* bPlane = (su < 4) ? Qh8 : Ql8;
  const int sCol = (su & 3) * 16;
  const int sRow = tid >> 3;               // + j*32

  // frag offsets (row&7 == lr&7 for all m/n/wm/wn since those are multiples of 8)
  const int pH = (lk ^ (lr & 7)) * 16;
  const int pL = ((4 | lk) ^ (lr & 7)) * 16;
  const int aOffH = (wm * 64 + lr) * 128 + pH;
  const int aOffL = (wm * 64 + lr) * 128 + pL;
  const int bOffH = 16384 + (wn * 32 + lr) * 128 + pH;
  const int bOffL = 16384 + (wn * 32 + lr) * 128 + pL;

  i32x4 hh[4][2] = {};
  i32x4 mid[4][2] = {};

  for (int kt = 0; kt < 512; kt += 64) {
    uint4 sg[6];
#pragma unroll
    for (int j = 0; j < 4; j++)
      sg[j] = *(const uint4*)(aPlane + (size_t)(mbase + sRow + j * 32) * 512 + kt + sCol);
#pragma unroll
    for (int j = 0; j < 2; j++)
      sg[4 + j] = *(const uint4*)(bPlane + (size_t)(nbase + sRow + j * 32) * 512 + kt + sCol);
    __syncthreads();
#pragma unroll
    for (int j = 0; j < 4; j++) *(uint4*)(lds + tid * 16 + j * 4096) = sg[j];
#pragma unroll
    for (int j = 0; j < 2; j++) *(uint4*)(lds + 16384 + tid * 16 + j * 4096) = sg[4 + j];
    __syncthreads();

    i32x4 bh[2], bl[2];
#pragma unroll
    for (int n = 0; n < 2; n++) {
      bh[n] = *(const i32x4*)(lds + bOffH + n * 2048);
      bl[n] = *(const i32x4*)(lds + bOffL + n * 2048);
    }
#pragma unroll
    for (int m = 0; m < 4; m++) {
      i32x4 ah = *(const i32x4*)(lds + aOffH + m * 2048);
      i32x4 al = *(const i32x4*)(lds + aOffL + m * 2048);
#pragma unroll
      for (int n = 0; n < 2; n++) {
        hh[m][n]  = mm_i8(ah, bh[n], hh[m][n]);
        mid[m][n] = mm_i8(ah, bl[n], mid[m][n]);
        mid[m][n] = mm_i8(al, bh[n], mid[m][n]);
      }
    }
  }

  // ---- epilogue: S = sq*sk*(65536*hh + 256*mid); mask*scale, chunk softmax, P' ----
  __syncthreads();
  float* sred = (float*)lds;            // [2 wm][64 q]
  float* ssum = sred + 128;
  u16* pb = (u16*)(lds + 1024);         // [64 q][136 kv]
  const int c = blockIdx.x;             // kv chunk (128 wide), NC = 64
  f32x4 sv[4][2];
  float mfin[2];
#pragma unroll
  for (int nt = 0; nt < 2; nt++) {
    const int q_l = wn * 32 + nt * 16 + lr;
    const float sq = sQ[nbase + q_l] * scale;
    const float* arow = Adj + (size_t)(nbase + q_l) * NN + mbase + wm * 64 + lk * 4;
    float mx = -3.4e38f;
#pragma unroll
    for (int mt = 0; mt < 4; mt++) {
      const float4 a4 = *(const float4*)(arow + mt * 16);
      const float4 sk4 = *(const float4*)(sK + mbase + wm * 64 + mt * 16 + lk * 4);
#pragma unroll
      for (int r = 0; r < 4; r++) {
        float s = (65536.f * (float)hh[mt][nt][r] + 256.f * (float)mid[mt][nt][r])
                  * sq * ((const float*)&sk4)[r] * ((const float*)&a4)[r];
        sv[mt][nt][r] = s;
        mx = fmaxf(mx, s);
      }
    }
    mx = fmaxf(mx, __shfl_xor(mx, 16));
    mx = fmaxf(mx, __shfl_xor(mx, 32));
    if (lane < 16) sred[wm * 64 + wn * 32 + nt * 16 + lane] = mx;
  }
  __syncthreads();
#pragma unroll
  for (int nt = 0; nt < 2; nt++) {
    const int qi = wn * 32 + nt * 16 + lr;
    mfin[nt] = fmaxf(sred[qi], sred[64 + qi]);
  }
  if (wm == 0 && lane < 16) {
#pragma unroll
    for (int nt = 0; nt < 2; nt++)
      mC[(size_t)c * NN + nbase + wn * 32 + nt * 16 + lane] = mfin[nt];
  }
#pragma unroll
  for (int nt = 0; nt < 2; nt++) {
    float sm = 0.f;
#pragma unroll
    for (int mt = 0; mt < 4; mt++)
#pragma unroll
      for (int r = 0; r < 4; r++) {
        float p = __expf(sv[mt][nt][r] - mfin[nt]);
        sv[mt][nt][r] = p;
        sm += p;
      }
    sm += __shfl_xor(sm, 16);
    sm += __shfl_xor(sm, 32);
    if (lane < 16) ssum[wm * 64 + wn * 32 + nt * 16 + lane] = sm;
  }
  __syncthreads();
  if (wm == 0 && lane < 16) {
#pragma unroll
    for (int nt = 0; nt < 2; nt++) {
      const int qi = wn * 32 + nt * 16 + lane;
      lC[(size_t)c * NN + nbase + qi] = ssum[qi] + ssum[64 + qi];
    }
  }
#pragma unroll
  for (int nt = 0; nt < 2; nt++) {
    const int q_l = wn * 32 + nt * 16 + lr;
#pragma unroll
    for (int mt = 0; mt < 4; mt++) {
      const int kvo = wm * 64 + mt * 16 + lk * 4;
      u32 u0 = (u32)f2bf(sv[mt][nt][0]) | ((u32)f2bf(sv[mt][nt][1]) << 16);
      u32 u1 = (u32)f2bf(sv[mt][nt][2]) | ((u32)f2bf(sv[mt][nt][3]) << 16);
      *(uint2*)&pb[q_l * 136 + kvo] = make_uint2(u0, u1);
    }
  }
  __syncthreads();
  {
    const int q_r = tid >> 2, qu = tid & 3;
    u16* dst = Pout + (size_t)(nbase + q_r) * NN + mbase + qu * 32;
    const u16* srcp = &pb[q_r * 136 + qu * 32];
    *(uint4*)dst = *(const uint4*)srcp;
    *(uint4*)(dst + 8) = *(const uint4*)(srcp + 8);
    *(uint4*)(dst + 16) = *(const uint4*)(srcp + 16);
    *(uint4*)(dst + 24) = *(const uint4*)(srcp + 24);
  }
}

// ---------------- k_big: PV GEMM (256x128 tile, 1-pass, K-split) ----------------

template<int EPI, int PASSES, int KSPLIT>
__launch_bounds__(256, 2)
__global__ void k_big(const u16* __restrict__ Ahi, const u16* __restrict__ Alo,
                      const u16* __restrict__ Bhi, const u16* __restrict__ Blo,
                      int M, int N, int K,
                      float* __restrict__ Cf, float* __restrict__ Cf1,
                      float* __restrict__ Cf2, float* __restrict__ Cf3,
                      const float* __restrict__ Fsc)
{
  __shared__ __align__(16) u16 lds[15360];
  u16* sAh = lds;
  u16* sBh = lds + 10240;

  const int tid = threadIdx.x, lane = tid & 63, wid = tid >> 6;
  const int wn = wid & 1, wm = wid >> 1;
  const int lr = lane & 15, lk = lane >> 4;
  const int mbase = blockIdx.x * 256, nbase = blockIdx.y * 128;
  const int srow = tid >> 1, shalf = tid & 1;
  const size_t Ks = (size_t)K;

  int kbeg = 0, kend = K;
  if constexpr (KSPLIT > 1) {
    const int steps = K >> 5, bz = blockIdx.z;
    kbeg = ((steps * bz) / KSPLIT) << 5;
    kend = ((steps * (bz + 1)) / KSPLIT) << 5;
  }

  f32x4 acc[8][4] = {};

  for (int kt = kbeg; kt < kend; kt += 32) {
    const size_t a0 = (size_t)(mbase + srow) * Ks + kt + shalf * 16;
    const size_t a1 = a0 + (size_t)128 * Ks;
    const size_t b0 = (size_t)(nbase + srow) * Ks + kt + shalf * 16;
    uint4 vah0 = *(const uint4*)(Ahi + a0), vah1 = *(const uint4*)(Ahi + a0 + 8);
    uint4 vah2 = *(const uint4*)(Ahi + a1), vah3 = *(const uint4*)(Ahi + a1 + 8);
    uint4 vbh0 = *(const uint4*)(Bhi + b0), vbh1 = *(const uint4*)(Bhi + b0 + 8);
    if constexpr (EPI == 3) {
      const float f0 = Fsc[((size_t)(kt >> 7) << 13) + mbase + srow];
      const float f1 = Fsc[((size_t)(kt >> 7) << 13) + mbase + 128 + srow];
      vah0 = scaleP(vah0, f0); vah1 = scaleP(vah1, f0);
      vah2 = scaleP(vah2, f1); vah3 = scaleP(vah3, f1);
    }
    __syncthreads();
    const int so = srow * 40 + shalf * 16;
    *(uint4*)(sAh + so) = vah0;        *(uint4*)(sAh + so + 8) = vah1;
    *(uint4*)(sAh + 5120 + so) = vah2; *(uint4*)(sAh + 5120 + so + 8) = vah3;
    *(uint4*)(sBh + so) = vbh0;        *(uint4*)(sBh + so + 8) = vbh1;
    __syncthreads();

    s16x8 ah[8];
#pragma unroll
    for (int m = 0; m < 8; m++)
      ah[m] = *(const s16x8*)(sAh + (wm * 128 + m * 16 + lr) * 40 + lk * 8);
#pragma unroll
    for (int nt = 0; nt < 4; nt++) {
      s16x8 bh = *(const s16x8*)(sBh + (wn * 64 + nt * 16 + lr) * 40 + lk * 8);
#pragma unroll
      for (int m = 0; m < 8; m++) acc[m][nt] = mm_bf16(ah[m], bh, acc[m][nt]);
    }
  }

  float* cfp = Cf;
  if constexpr (KSPLIT > 1) {
    if (blockIdx.z == 1) cfp = Cf1;
    else if (blockIdx.z == 2) cfp = Cf2;
    else if (blockIdx.z == 3) cfp = Cf3;
  }
#pragma unroll
  for (int mt = 0; mt < 8; mt++)
#pragma unroll
    for (int nt = 0; nt < 4; nt++) {
      const int grow = mbase + wm * 128 + mt * 16 + lk * 4;
      const int gcol = nbase + wn * 64 + nt * 16 + lr;
#pragma unroll
      for (int r = 0; r < 4; r++)
        cfp[(size_t)(grow + r) * N + gcol] = acc[mt][nt][r];
    }
}

// ---------------- projections GEMM (proven 128x128 template) ----------------

__launch_bounds__(256, 4)
__global__ void gemm_bt(const u16* __restrict__ Ahi, const u16* __restrict__ Alo,
                        const u16* __restrict__ Bhi, const u16* __restrict__ Blo,
                        int M, int N, int K,
                        u16* __restrict__ C0, u16* __restrict__ C1)
{
  constexpr int BUF = 128 * 40;
  __shared__ __align__(16) u16 lds[BUF * 4];

  u16* sAh = lds;
  u16* sAl = lds + BUF;
  u16* sBh = lds + 2 * BUF;
  u16* sBl = lds + 3 * BUF;

  const int tid = threadIdx.x, lane = tid & 63, wid = tid >> 6;
  const int wm = wid & 1, wn = wid >> 1;
  const int lr = lane & 15, lk = lane >> 4;
  const int mbase = blockIdx.x * 128;
  const int w = blockIdx.y >> 2;
  const int nbase = (blockIdx.y & 3) * 128;
  const u16 *bhp = Bhi + (size_t)w * 262144, *blp = Blo + (size_t)w * 262144;
  u16 *c0 = C0 + (size_t)w * 4194304, *c1 = C1 + (size_t)w * 4194304;
  const int srow = tid >> 1, shalf = tid & 1;
  const size_t Ks = (size_t)K;

  f32x4 acc[4][4] = {};

  for (int kt = 0; kt < K; kt += 32) {
    const size_t aoff = (size_t)(mbase + srow) * Ks + kt + shalf * 16;
    const size_t boff = (size_t)(nbase + srow) * Ks + kt + shalf * 16;
    uint4 vah0 = *(const uint4*)(Ahi + aoff), vah1 = *(const uint4*)(Ahi + aoff + 8);
    uint4 vbh0 = *(const uint4*)(bhp + boff), vbh1 = *(const uint4*)(bhp + boff + 8);
    uint4 val0 = *(const uint4*)(Alo + aoff), val1 = *(const uint4*)(Alo + aoff + 8);
    uint4 vbl0 = *(const uint4*)(blp + boff), vbl1 = *(const uint4*)(blp + boff + 8);
    __syncthreads();
    const int so = srow * 40 + shalf * 16;
    *(uint4*)(sAh + so) = vah0; *(uint4*)(sAh + so + 8) = vah1;
    *(uint4*)(sBh + so) = vbh0; *(uint4*)(sBh + so + 8) = vbh1;
    *(uint4*)(sAl + so) = val0; *(uint4*)(sAl + so + 8) = val1;
    *(uint4*)(sBl + so) = vbl0; *(uint4*)(sBl + so + 8) = vbl1;
    __syncthreads();

    s16x8 ah[4], bh[4], al[4], bl[4];
#pragma unroll
    for (int t = 0; t < 4; t++) {
      ah[t] = *(const s16x8*)(sAh + (wm * 64 + t * 16 + lr) * 40 + lk * 8);
      bh[t] = *(const s16x8*)(sBh + (wn * 64 + t * 16 + lr) * 40 + lk * 8);
      al[t] = *(const s16x8*)(sAl + (wm * 64 + t * 16 + lr) * 40 + lk * 8);
      bl[t] = *(const s16x8*)(sBl + (wn * 64 + t * 16 + lr) * 40 + lk * 8);
    }
#pragma unroll
    for (int mt = 0; mt < 4; mt++)
#pragma unroll
      for (int nt = 0; nt < 4; nt++) {
        acc[mt][nt] = mm_bf16(ah[mt], bh[nt], acc[mt][nt]);
        acc[mt][nt] = mm_bf16(ah[mt], bl[nt], acc[mt][nt]);
        acc[mt][nt] = mm_bf16(al[mt], bh[nt], acc[mt][nt]);
      }
  }

#pragma unroll
  for (int mt = 0; mt < 4; mt++)
#pragma unroll
    for (int nt = 0; nt < 4; nt++) {
      const int grow = mbase + wm * 64 + mt * 16 + lk * 4;
      const int gcol = nbase + wn * 64 + nt * 16 + lr;
#pragma unroll
      for (int r = 0; r < 4; r++) {
        float c = acc[mt][nt][r];
        size_t o = (size_t)(grow + r) * N + gcol;
        u16 h = f2bf(c);
        c0[o] = h;
        c1[o] = f2bf(c - bf2f(h));
      }
    }
}

// ---------------- softmax cross-chunk reduce ----------------

__global__ void k_reduce(const float* __restrict__ mC, const float* __restrict__ lC, float* __restrict__ F,
                         int NQ, int NC) {
  const int q = blockIdx.x * 256 + threadIdx.x;
  if (q >= NQ) return;
  float mf = -3.4e38f;
  for (int c = 0; c < NC; c++) mf = fmaxf(mf, mC[(size_t)c * NQ + q]);
  float L = 0.f;
  for (int c = 0; c < NC; c++) L += lC[(size_t)c * NQ + q] * __expf(mC[(size_t)c * NQ + q] - mf);
  const float inv = 1.0f / L;
  for (int c = 0; c < NC; c++) F[(size_t)c * NQ + q] = __expf(mC[(size_t)c * NQ + q] - mf) * inv;
}

__global__ void k_sumout3(float* __restrict__ out, const float* __restrict__ p1,
                          const float* __restrict__ p2, const float* __restrict__ p3, int n4) {
  int i = blockIdx.x * 256 + threadIdx.x;
  if (i >= n4) return;
  float4 o = ((const float4*)out)[i];
  float4 a = ((const float4*)p1)[i];
  float4 b = ((const float4*)p2)[i];
  float4 c = ((const float4*)p3)[i];
  o.x += a.x + b.x + c.x; o.y += a.y + b.y + c.y;
  o.z += a.z + b.z + c.z; o.w += a.w + b.w + c.w;
  ((float4*)out)[i] = o;
}

// ---------------- launcher ----------------

extern "C" void kernel_launch(void* const* d_in, const int* in_sizes, int n_in,
                              void* d_out, int out_size, void* d_ws, size_t ws_size,
                              hipStream_t stream) {
  const float* H  = (const float*)d_in[0];
  const float* Aj = (const float*)d_in[1];
  const float* Wq = (const float*)d_in[2];
  const float* Wk = (const float*)d_in[3];
  const float* Wv = (const float*)d_in[4];
  float* out = (float*)d_out;
  const int NN = 8192, DD = 512;

  char* ws = (char*)d_ws;
  size_t off = 0;
  auto alloc = [&](size_t bytes) -> void* {
    void* p = ws + off;
    off += (bytes + 255) & ~(size_t)255;
    return p;
  };
  u16* Pbuf  = (u16*)alloc((size_t)NN * NN * 2);           // 128 MB
  u16* Hhi   = (u16*)alloc((size_t)NN * DD * 2);
  u16* Hlo   = (u16*)alloc((size_t)NN * DD * 2);
  u16* WThi  = (u16*)alloc((size_t)3 * DD * DD * 2);
  u16* WTlo  = (u16*)alloc((size_t)3 * DD * DD * 2);
  u16* PRhi  = (u16*)alloc((size_t)3 * NN * DD * 2);       // [HQ|HK|HV] hi
  u16* PRlo  = (u16*)alloc((size_t)3 * NN * DD * 2);
  u16* HVthi = (u16*)alloc((size_t)NN * DD * 2);
  float* mC  = (float*)alloc((size_t)64 * NN * 4);
  float* lC  = (float*)alloc((size_t)64 * NN * 4);
  float* Ft  = (float*)alloc((size_t)64 * NN * 4);
  char* Qh8  = (char*)alloc((size_t)NN * DD);
  char* Ql8  = (char*)alloc((size_t)NN * DD);
  char* Kh8  = (char*)alloc((size_t)NN * DD);
  char* Kl8  = (char*)alloc((size_t)NN * DD);
  float* sQ  = (float*)alloc((size_t)NN * 4);
  float* sK  = (float*)alloc((size_t)NN * 4);
  if (off > ws_size) return;  // workspace too small -> visible failure

  u16* HQhi = PRhi;                 u16* HQlo = PRlo;
  u16* HKhi = PRhi + (size_t)NN*DD; u16* HKlo = PRlo + (size_t)NN*DD;
  u16* HVhi = PRhi + (size_t)2*NN*DD;

  // K-split partials for PV: alias the dead region (Hhi..PRlo dead by then)
  float* part1 = (float*)Hhi;                              // 3 x 16.78 MB
  float* part2 = part1 + (size_t)NN * DD;
  float* part3 = part2 + (size_t)NN * DD;

  const float scl = 1.0f / sqrtf((float)DD);

  k_split<<<4096, 256, 0, stream>>>(H, Hhi, Hlo, NN * DD / 4);
  k_prepW<<<3072, 256, 0, stream>>>(Wq, Wk, Wv, WThi, WTlo);

  // fused Q/K/V projections: grid y = {w}*4 + {n-tile}
  dim3 gP(64, 12);
  gemm_bt<<<gP, 256, 0, stream>>>(Hhi, Hlo, WThi, WTlo, NN, DD, DD, PRhi, PRlo);

  dim3 gT(128, 8);
  k_transpose<<<gT, 256, 0, stream>>>(HVhi, HVthi, NN, DD);

  k_quant<<<2048, 256, 0, stream>>>(HQhi, HQlo, Qh8, Ql8, sQ);
  k_quant<<<2048, 256, 0, stream>>>(HKhi, HKlo, Kh8, Kl8, sK);

  // scores: i8 MFMA, 128(kv) x 64(q) tiles; chunk = 128 kv (NC = 64 unchanged)
  dim3 gS(64, 128);
  k_iscore<<<gS, 256, 0, stream>>>(Kh8, Kl8, Qh8, Ql8, sK, sQ,
                                   Aj, mC, lC, Pbuf, scl);

  k_reduce<<<32, 256, 0, stream>>>(mC, lC, Ft, NN, 64);

  // PV: out = (P'*F) @ HVt^T, 1-pass, 256x128 tiles, K split 4-way
  dim3 gO(32, 4, 4);
  k_big<3, 1, 4><<<gO, 256, 0, stream>>>(Pbuf, nullptr, HVthi, nullptr, NN, DD, NN,
                                         out, part1, part2, part3, Ft);

  k_sumout3<<<4096, 256, 0, stream>>>(out, part1, part2, part3, NN * DD / 4);
}

// Round 10
// 444.569 us; speedup vs baseline: 1.8431x; 1.8431x over previous
//
#include <hip/hip_runtime.h>
#include <cmath>

// SimplicialAttentionLayer: out = softmax((H Wq)(H Wk)^T * A / sqrt(D)) @ (H Wv)
// N=8192, D=512, fp32.
//  gemm_bt: fused 3-projection GEMM -> HQ/HK/HV hi/lo bf16 (proven 128x128)
//  k_quant: HQ/HK -> per-row-scaled int16 split into hi8/lo8 planes + sQ/sK
//  k_iscore: scores via i8 MFMA (16x16x64), 3 passes into 2 i32 accs
//            (S = sq*sk*(65536*hh + 256*mid)); gll-staged 2-barrier skeleton,
//            128(kv)x64(q) tile, packed hi|lo 128-B LDS rows, slot-XOR swizzle.
//            Scores converted IN-PLACE into mid regs (no sv array -> no spill).
//  k_reduce: F[c][q] = exp(m_c - m_fin)/L
//  k_big<3,1,4>: PV 1-pass bf16, F folded into staging, K-split 4-way
//  k_sumout3: fold partials

typedef unsigned short u16;
typedef unsigned int   u32;
typedef float f32x4 __attribute__((ext_vector_type(4)));
typedef short s16x8 __attribute__((ext_vector_type(8)));
typedef int   i32x4 __attribute__((ext_vector_type(4)));

#define DEVI static __device__ __forceinline__

DEVI u16 f2bf(float x) { u32 u = __float_as_uint(x); u32 r = u + 0x7fffu + ((u >> 16) & 1u); return (u16)(r >> 16); }
DEVI float bf2f(u16 b) { return __uint_as_float((u32)b << 16); }

DEVI f32x4 mm_bf16(s16x8 a, s16x8 b, f32x4 c) {
  return __builtin_amdgcn_mfma_f32_16x16x32_bf16(a, b, c, 0, 0, 0);
}
DEVI i32x4 mm_i8(i32x4 a, i32x4 b, i32x4 c) {
  return __builtin_amdgcn_mfma_i32_16x16x64_i8(a, b, c, 0, 0, 0);
}

// async global->LDS, 16 B per lane (dest: wave-uniform base + lane*16)
DEVI void gllc(const char* g, char* l) {
  __builtin_amdgcn_global_load_lds((const __attribute__((address_space(1))) void*)g,
                                   (__attribute__((address_space(3))) void*)l, 16, 0, 0);
}

// scale 8 packed bf16 by f, round-nearest, repack via v_perm
DEVI uint4 scaleP(uint4 v, float f) {
  u32* w = (u32*)&v;
#pragma unroll
  for (int j = 0; j < 4; j++) {
    u32 lo = __float_as_uint(__uint_as_float(w[j] << 16) * f) + 0x8000u;
    u32 hi = __float_as_uint(__uint_as_float(w[j] & 0xffff0000u) * f) + 0x8000u;
    w[j] = __builtin_amdgcn_perm(hi, lo, 0x07060302);
  }
  return v;
}

// ---------------- elementwise prep kernels ----------------

__global__ void k_split(const float* __restrict__ X, u16* __restrict__ Xhi, u16* __restrict__ Xlo, int n4) {
  int i = blockIdx.x * 256 + threadIdx.x;
  if (i >= n4) return;
  float4 v = ((const float4*)X)[i];
  u16 h0 = f2bf(v.x), h1 = f2bf(v.y), h2 = f2bf(v.z), h3 = f2bf(v.w);
  u16 l0 = f2bf(v.x - bf2f(h0)), l1 = f2bf(v.y - bf2f(h1));
  u16 l2 = f2bf(v.z - bf2f(h2)), l3 = f2bf(v.w - bf2f(h3));
  ((uint2*)Xhi)[i] = make_uint2((u32)h0 | ((u32)h1 << 16), (u32)h2 | ((u32)h3 << 16));
  ((uint2*)Xlo)[i] = make_uint2((u32)l0 | ((u32)l1 << 16), (u32)l2 | ((u32)l3 << 16));
}

__global__ void k_prepW(const float* __restrict__ W0, const float* __restrict__ W1, const float* __restrict__ W2,
                        u16* __restrict__ Thi, u16* __restrict__ Tlo) {
  int idx = blockIdx.x * 256 + threadIdx.x;
  if (idx >= 3 * 512 * 512) return;
  int w = idx >> 18, n = (idx >> 9) & 511, k = idx & 511;
  const float* W = (w == 0) ? W0 : (w == 1) ? W1 : W2;
  float v = W[k * 512 + n];
  u16 h = f2bf(v);
  Thi[idx] = h;
  Tlo[idx] = f2bf(v - bf2f(h));
}

__global__ void k_transpose(const u16* __restrict__ in, u16* __restrict__ out, int R, int C) {
  __shared__ u16 t[64][72];
  const int rb = blockIdx.x * 64, cb = blockIdx.y * 64;
  const int r = threadIdx.x >> 2, c4 = (threadIdx.x & 3) * 16;
  const u16* src = in + (size_t)(rb + r) * C + cb + c4;
  *(uint4*)&t[r][c4] = *(const uint4*)src;
  *(uint4*)&t[r][c4 + 8] = *(const uint4*)(src + 8);
  __syncthreads();
  u16 v[16];
#pragma unroll
  for (int j = 0; j < 16; j++) v[j] = t[c4 + j][r];
  uint4 o0, o1;
  o0.x = v[0] | ((u32)v[1] << 16); o0.y = v[2] | ((u32)v[3] << 16);
  o0.z = v[4] | ((u32)v[5] << 16); o0.w = v[6] | ((u32)v[7] << 16);
  o1.x = v[8] | ((u32)v[9] << 16); o1.y = v[10] | ((u32)v[11] << 16);
  o1.z = v[12] | ((u32)v[13] << 16); o1.w = v[14] | ((u32)v[15] << 16);
  u16* dst = out + (size_t)(cb + r) * R + rb + c4;
  *(uint4*)dst = o0;
  *(uint4*)(dst + 8) = o1;
}

// ---------------- int16 row-quantization: x ~ s*(256*h8 + l8) ----------------

__global__ void k_quant(const u16* __restrict__ hi, const u16* __restrict__ lo,
                        char* __restrict__ q8h, char* __restrict__ q8l, float* __restrict__ sc) {
  const int row = blockIdx.x * 4 + (threadIdx.x >> 6);
  const int lane = threadIdx.x & 63;
  const size_t base = (size_t)row * 512 + lane * 8;
  uint4 vh = *(const uint4*)(hi + base);
  uint4 vl = *(const uint4*)(lo + base);
  const u32* ph = (const u32*)&vh;
  const u32* pl = (const u32*)&vl;
  float x[8];
#pragma unroll
  for (int j = 0; j < 4; j++) {
    x[2 * j]     = bf2f((u16)(ph[j] & 0xffff)) + bf2f((u16)(pl[j] & 0xffff));
    x[2 * j + 1] = bf2f((u16)(ph[j] >> 16))    + bf2f((u16)(pl[j] >> 16));
  }
  float amax = 0.f;
#pragma unroll
  for (int j = 0; j < 8; j++) amax = fmaxf(amax, fabsf(x[j]));
#pragma unroll
  for (int d = 1; d < 64; d <<= 1) amax = fmaxf(amax, __shfl_xor(amax, d));
  amax = fmaxf(amax, 1e-30f);
  const float s = amax * (1.0f / 32512.f);
  const float inv = 32512.f / amax;
  u32 hb0 = 0, hb1 = 0, lb0 = 0, lb1 = 0;
#pragma unroll
  for (int j = 0; j < 8; j++) {
    int v = (int)rintf(x[j] * inv);
    int h = (v + 128) >> 8;
    int l = v - (h << 8);
    if (j < 4) { hb0 |= (u32)(h & 255) << (j * 8);       lb0 |= (u32)(l & 255) << (j * 8); }
    else       { hb1 |= (u32)(h & 255) << ((j - 4) * 8); lb1 |= (u32)(l & 255) << ((j - 4) * 8); }
  }
  *(uint2*)(q8h + base) = make_uint2(hb0, hb1);
  *(uint2*)(q8l + base) = make_uint2(lb0, lb1);
  if (lane == 0) sc[row] = s;
}

// ---------------- k_iscore: i8 scores, 128(kv) x 64(q) tile, 4 waves ----------------
// LDS: A-region [128 rows][128 B] (8x16B units: u<4 = hi chunk u, u>=4 = lo chunk u-4,
// phys slot p = u ^ (row&7)); B-region [64 rows][128 B] at +16384.
// Staging: global_load_lds (dest linear tid*16 + j*4096; swizzle in SOURCE addr).
// Epilogue: scores converted in-place into mid regs (hh dies) -> no spill.

__launch_bounds__(256, 4)
__global__ void k_iscore(const char* __restrict__ Kh8, const char* __restrict__ Kl8,
                         const char* __restrict__ Qh8, const char* __restrict__ Ql8,
                         const float* __restrict__ sK, const float* __restrict__ sQ,
                         const float* __restrict__ Adj, float* __restrict__ mC,
                         float* __restrict__ lC, u16* __restrict__ Pout, float scale)
{
  constexpr int NN = 8192;
  __shared__ __align__(16) char lds[24576];

  const int tid = threadIdx.x, lane = tid & 63, wid = tid >> 6;
  const int wm = wid >> 1, wn = wid & 1;   // wave: kv [wm*64,+64) x q [wn*32,+32)
  const int lr = lane & 15, lk = lane >> 4;
  const int mbase = blockIdx.x * 128, nbase = blockIdx.y * 64;

  // staging: round j dest byte = tid*16 + j*4096; logical unit is j-invariant
  const int su = (tid & 7) ^ ((tid >> 3) & 7);
  const char* aPlane = (su < 4) ? Kh8 : Kl8;
  const char* bPlane = (su < 4) ? Qh8 : Ql8;
  const int sCol = (su & 3) * 16;
  const int sRow = tid >> 3;               // + j*32

  // frag offsets (row&7 == lr&7 since m/n offsets are multiples of 8... of 16)
  const int pH = (lk ^ (lr & 7)) * 16;
  const int pL = ((4 | lk) ^ (lr & 7)) * 16;
  const int aOffH = (wm * 64 + lr) * 128 + pH;
  const int aOffL = (wm * 64 + lr) * 128 + pL;
  const int bOffH = 16384 + (wn * 32 + lr) * 128 + pH;
  const int bOffL = 16384 + (wn * 32 + lr) * 128 + pL;

  i32x4 hh[4][2] = {};
  i32x4 mid[4][2] = {};

  for (int kt = 0; kt < 512; kt += 64) {
    __syncthreads();                       // prev tile fully consumed
#pragma unroll
    for (int j = 0; j < 4; j++)
      gllc(aPlane + (size_t)(mbase + sRow + j * 32) * 512 + kt + sCol,
           lds + tid * 16 + j * 4096);
#pragma unroll
    for (int j = 0; j < 2; j++)
      gllc(bPlane + (size_t)(nbase + sRow + j * 32) * 512 + kt + sCol,
           lds + 16384 + tid * 16 + j * 4096);
    asm volatile("s_waitcnt vmcnt(0)" ::: "memory");
    __syncthreads();                       // all waves' DMA complete

    i32x4 bh[2], bl[2];
#pragma unroll
    for (int n = 0; n < 2; n++) {
      bh[n] = *(const i32x4*)(lds + bOffH + n * 2048);
      bl[n] = *(const i32x4*)(lds + bOffL + n * 2048);
    }
#pragma unroll
    for (int m = 0; m < 4; m++) {
      i32x4 ah = *(const i32x4*)(lds + aOffH + m * 2048);
      i32x4 al = *(const i32x4*)(lds + aOffL + m * 2048);
#pragma unroll
      for (int n = 0; n < 2; n++) {
        hh[m][n]  = mm_i8(ah, bh[n], hh[m][n]);
        mid[m][n] = mm_i8(ah, bl[n], mid[m][n]);
        mid[m][n] = mm_i8(al, bh[n], mid[m][n]);
      }
    }
  }

  // ---- epilogue: S = sq*sk*(65536*hh + 256*mid) IN-PLACE into mid (float bits) ----
  __syncthreads();
  float* sred = (float*)lds;            // [2 wm][64 q]
  float* ssum = sred + 128;
  u16* pb = (u16*)(lds + 1024);         // [64 q][136 kv]
  const int c = blockIdx.x;             // kv chunk (128 wide), NC = 64
  float mfin[2];
#pragma unroll
  for (int nt = 0; nt < 2; nt++) {
    const int q_l = wn * 32 + nt * 16 + lr;
    const float sq = sQ[nbase + q_l] * scale;
    const float* arow = Adj + (size_t)(nbase + q_l) * NN + mbase + wm * 64 + lk * 4;
    float mx = -3.4e38f;
#pragma unroll
    for (int mt = 0; mt < 4; mt++) {
      const float4 a4 = *(const float4*)(arow + mt * 16);
      const float4 sk4 = *(const float4*)(sK + mbase + wm * 64 + mt * 16 + lk * 4);
#pragma unroll
      for (int r = 0; r < 4; r++) {
        float s = (65536.f * (float)hh[mt][nt][r] + 256.f * (float)mid[mt][nt][r])
                  * sq * ((const float*)&sk4)[r] * ((const float*)&a4)[r];
        mid[mt][nt][r] = __float_as_int(s);
        mx = fmaxf(mx, s);
      }
    }
    mx = fmaxf(mx, __shfl_xor(mx, 16));
    mx = fmaxf(mx, __shfl_xor(mx, 32));
    if (lane < 16) sred[wm * 64 + wn * 32 + nt * 16 + lane] = mx;
  }
  __syncthreads();
#pragma unroll
  for (int nt = 0; nt < 2; nt++) {
    const int qi = wn * 32 + nt * 16 + lr;
    mfin[nt] = fmaxf(sred[qi], sred[64 + qi]);
  }
  if (wm == 0 && lane < 16) {
#pragma unroll
    for (int nt = 0; nt < 2; nt++)
      mC[(size_t)c * NN + nbase + wn * 32 + nt * 16 + lane] = mfin[nt];
  }
#pragma unroll
  for (int nt = 0; nt < 2; nt++) {
    float sm = 0.f;
#pragma unroll
    for (int mt = 0; mt < 4; mt++)
#pragma unroll
      for (int r = 0; r < 4; r++) {
        float p = __expf(__int_as_float(mid[mt][nt][r]) - mfin[nt]);
        mid[mt][nt][r] = __float_as_int(p);
        sm += p;
      }
    sm += __shfl_xor(sm, 16);
    sm += __shfl_xor(sm, 32);
    if (lane < 16) ssum[wm * 64 + wn * 32 + nt * 16 + lane] = sm;
  }
  __syncthreads();
  if (wm == 0 && lane < 16) {
#pragma unroll
    for (int nt = 0; nt < 2; nt++) {
      const int qi = wn * 32 + nt * 16 + lane;
      lC[(size_t)c * NN + nbase + qi] = ssum[qi] + ssum[64 + qi];
    }
  }
#pragma unroll
  for (int nt = 0; nt < 2; nt++) {
    const int q_l = wn * 32 + nt * 16 + lr;
#pragma unroll
    for (int mt = 0; mt < 4; mt++) {
      const int kvo = wm * 64 + mt * 16 + lk * 4;
      u32 u0 = (u32)f2bf(__int_as_float(mid[mt][nt][0])) |
               ((u32)f2bf(__int_as_float(mid[mt][nt][1])) << 16);
      u32 u1 = (u32)f2bf(__int_as_float(mid[mt][nt][2])) |
               ((u32)f2bf(__int_as_float(mid[mt][nt][3])) << 16);
      *(uint2*)&pb[q_l * 136 + kvo] = make_uint2(u0, u1);
    }
  }
  __syncthreads();
  {
    const int q_r = tid >> 2, qu = tid & 3;
    u16* dst = Pout + (size_t)(nbase + q_r) * NN + mbase + qu * 32;
    const u16* srcp = &pb[q_r * 136 + qu * 32];
    *(uint4*)dst = *(const uint4*)srcp;
    *(uint4*)(dst + 8) = *(const uint4*)(srcp + 8);
    *(uint4*)(dst + 16) = *(const uint4*)(srcp + 16);
    *(uint4*)(dst + 24) = *(const uint4*)(srcp + 24);
  }
}

// ---------------- k_big: PV GEMM (256x128 tile, 1-pass, K-split) ----------------

template<int EPI, int PASSES, int KSPLIT>
__launch_bounds__(256, 2)
__global__ void k_big(const u16* __restrict__ Ahi, const u16* __restrict__ Alo,
                      const u16* __restrict__ Bhi, const u16* __restrict__ Blo,
                      int M, int N, int K,
                      float* __restrict__ Cf, float* __restrict__ Cf1,
                      float* __restrict__ Cf2, float* __restrict__ Cf3,
                      const float* __restrict__ Fsc)
{
  __shared__ __align__(16) u16 lds[15360];
  u16* sAh = lds;
  u16* sBh = lds + 10240;

  const int tid = threadIdx.x, lane = tid & 63, wid = tid >> 6;
  const int wn = wid & 1, wm = wid >> 1;
  const int lr = lane & 15, lk = lane >> 4;
  const int mbase = blockIdx.x * 256, nbase = blockIdx.y * 128;
  const int srow = tid >> 1, shalf = tid & 1;
  const size_t Ks = (size_t)K;

  int kbeg = 0, kend = K;
  if constexpr (KSPLIT > 1) {
    const int steps = K >> 5, bz = blockIdx.z;
    kbeg = ((steps * bz) / KSPLIT) << 5;
    kend = ((steps * (bz + 1)) / KSPLIT) << 5;
  }

  f32x4 acc[8][4] = {};

  for (int kt = kbeg; kt < kend; kt += 32) {
    const size_t a0 = (size_t)(mbase + srow) * Ks + kt + shalf * 16;
    const size_t a1 = a0 + (size_t)128 * Ks;
    const size_t b0 = (size_t)(nbase + srow) * Ks + kt + shalf * 16;
    uint4 vah0 = *(const uint4*)(Ahi + a0), vah1 = *(const uint4*)(Ahi + a0 + 8);
    uint4 vah2 = *(const uint4*)(Ahi + a1), vah3 = *(const uint4*)(Ahi + a1 + 8);
    uint4 vbh0 = *(const uint4*)(Bhi + b0), vbh1 = *(const uint4*)(Bhi + b0 + 8);
    if constexpr (EPI == 3) {
      const float f0 = Fsc[((size_t)(kt >> 7) << 13) + mbase + srow];
      const float f1 = Fsc[((size_t)(kt >> 7) << 13) + mbase + 128 + srow];
      vah0 = scaleP(vah0, f0); vah1 = scaleP(vah1, f0);
      vah2 = scaleP(vah2, f1); vah3 = scaleP(vah3, f1);
    }
    __syncthreads();
    const int so = srow * 40 + shalf * 16;
    *(uint4*)(sAh + so) = vah0;        *(uint4*)(sAh + so + 8) = vah1;
    *(uint4*)(sAh + 5120 + so) = vah2; *(uint4*)(sAh + 5120 + so + 8) = vah3;
    *(uint4*)(sBh + so) = vbh0;        *(uint4*)(sBh + so + 8) = vbh1;
    __syncthreads();

    s16x8 ah[8];
#pragma unroll
    for (int m = 0; m < 8; m++)
      ah[m] = *(const s16x8*)(sAh + (wm * 128 + m * 16 + lr) * 40 + lk * 8);
#pragma unroll
    for (int nt = 0; nt < 4; nt++) {
      s16x8 bh = *(const s16x8*)(sBh + (wn * 64 + nt * 16 + lr) * 40 + lk * 8);
#pragma unroll
      for (int m = 0; m < 8; m++) acc[m][nt] = mm_bf16(ah[m], bh, acc[m][nt]);
    }
  }

  float* cfp = Cf;
  if constexpr (KSPLIT > 1) {
    if (blockIdx.z == 1) cfp = Cf1;
    else if (blockIdx.z == 2) cfp = Cf2;
    else if (blockIdx.z == 3) cfp = Cf3;
  }
#pragma unroll
  for (int mt = 0; mt < 8; mt++)
#pragma unroll
    for (int nt = 0; nt < 4; nt++) {
      const int grow = mbase + wm * 128 + mt * 16 + lk * 4;
      const int gcol = nbase + wn * 64 + nt * 16 + lr;
#pragma unroll
      for (int r = 0; r < 4; r++)
        cfp[(size_t)(grow + r) * N + gcol] = acc[mt][nt][r];
    }
}

// ---------------- projections GEMM (proven 128x128 template) ----------------

__launch_bounds__(256, 4)
__global__ void gemm_bt(const u16* __restrict__ Ahi, const u16* __restrict__ Alo,
                        const u16* __restrict__ Bhi, const u16* __restrict__ Blo,
                        int M, int N, int K,
                        u16* __restrict__ C0, u16* __restrict__ C1)
{
  constexpr int BUF = 128 * 40;
  __shared__ __align__(16) u16 lds[BUF * 4];

  u16* sAh = lds;
  u16* sAl = lds + BUF;
  u16* sBh = lds + 2 * BUF;
  u16* sBl = lds + 3 * BUF;

  const int tid = threadIdx.x, lane = tid & 63, wid = tid >> 6;
  const int wm = wid & 1, wn = wid >> 1;
  const int lr = lane & 15, lk = lane >> 4;
  const int mbase = blockIdx.x * 128;
  const int w = blockIdx.y >> 2;
  const int nbase = (blockIdx.y & 3) * 128;
  const u16 *bhp = Bhi + (size_t)w * 262144, *blp = Blo + (size_t)w * 262144;
  u16 *c0 = C0 + (size_t)w * 4194304, *c1 = C1 + (size_t)w * 4194304;
  const int srow = tid >> 1, shalf = tid & 1;
  const size_t Ks = (size_t)K;

  f32x4 acc[4][4] = {};

  for (int kt = 0; kt < K; kt += 32) {
    const size_t aoff = (size_t)(mbase + srow) * Ks + kt + shalf * 16;
    const size_t boff = (size_t)(nbase + srow) * Ks + kt + shalf * 16;
    uint4 vah0 = *(const uint4*)(Ahi + aoff), vah1 = *(const uint4*)(Ahi + aoff + 8);
    uint4 vbh0 = *(const uint4*)(bhp + boff), vbh1 = *(const uint4*)(bhp + boff + 8);
    uint4 val0 = *(const uint4*)(Alo + aoff), val1 = *(const uint4*)(Alo + aoff + 8);
    uint4 vbl0 = *(const uint4*)(blp + boff), vbl1 = *(const uint4*)(blp + boff + 8);
    __syncthreads();
    const int so = srow * 40 + shalf * 16;
    *(uint4*)(sAh + so) = vah0; *(uint4*)(sAh + so + 8) = vah1;
    *(uint4*)(sBh + so) = vbh0; *(uint4*)(sBh + so + 8) = vbh1;
    *(uint4*)(sAl + so) = val0; *(uint4*)(sAl + so + 8) = val1;
    *(uint4*)(sBl + so) = vbl0; *(uint4*)(sBl + so + 8) = vbl1;
    __syncthreads();

    s16x8 ah[4], bh[4], al[4], bl[4];
#pragma unroll
    for (int t = 0; t < 4; t++) {
      ah[t] = *(const s16x8*)(sAh + (wm * 64 + t * 16 + lr) * 40 + lk * 8);
      bh[t] = *(const s16x8*)(sBh + (wn * 64 + t * 16 + lr) * 40 + lk * 8);
      al[t] = *(const s16x8*)(sAl + (wm * 64 + t * 16 + lr) * 40 + lk * 8);
      bl[t] = *(const s16x8*)(sBl + (wn * 64 + t * 16 + lr) * 40 + lk * 8);
    }
#pragma unroll
    for (int mt = 0; mt < 4; mt++)
#pragma unroll
      for (int nt = 0; nt < 4; nt++) {
        acc[mt][nt] = mm_bf16(ah[mt], bh[nt], acc[mt][nt]);
        acc[mt][nt] = mm_bf16(ah[mt], bl[nt], acc[mt][nt]);
        acc[mt][nt] = mm_bf16(al[mt], bh[nt], acc[mt][nt]);
      }
  }

#pragma unroll
  for (int mt = 0; mt < 4; mt++)
#pragma unroll
    for (int nt = 0; nt < 4; nt++) {
      const int grow = mbase + wm * 64 + mt * 16 + lk * 4;
      const int gcol = nbase + wn * 64 + nt * 16 + lr;
#pragma unroll
      for (int r = 0; r < 4; r++) {
        float c = acc[mt][nt][r];
        size_t o = (size_t)(grow + r) * N + gcol;
        u16 h = f2bf(c);
        c0[o] = h;
        c1[o] = f2bf(c - bf2f(h));
      }
    }
}

// ---------------- softmax cross-chunk reduce ----------------

__global__ void k_reduce(const float* __restrict__ mC, const float* __restrict__ lC, float* __restrict__ F,
                         int NQ, int NC) {
  const int q = blockIdx.x * 256 + threadIdx.x;
  if (q >= NQ) return;
  float mf = -3.4e38f;
  for (int c = 0; c < NC; c++) mf = fmaxf(mf, mC[(size_t)c * NQ + q]);
  float L = 0.f;
  for (int c = 0; c < NC; c++) L += lC[(size_t)c * NQ + q] * __expf(mC[(size_t)c * NQ + q] - mf);
  const float inv = 1.0f / L;
  for (int c = 0; c < NC; c++) F[(size_t)c * NQ + q] = __expf(mC[(size_t)c * NQ + q] - mf) * inv;
}

__global__ void k_sumout3(float* __restrict__ out, const float* __restrict__ p1,
                          const float* __restrict__ p2, const float* __restrict__ p3, int n4) {
  int i = blockIdx.x * 256 + threadIdx.x;
  if (i >= n4) return;
  float4 o = ((const float4*)out)[i];
  float4 a = ((const float4*)p1)[i];
  float4 b = ((const float4*)p2)[i];
  float4 c = ((const float4*)p3)[i];
  o.x += a.x + b.x + c.x; o.y += a.y + b.y + c.y;
  o.z += a.z + b.z + c.z; o.w += a.w + b.w + c.w;
  ((float4*)out)[i] = o;
}

// ---------------- launcher ----------------

extern "C" void kernel_launch(void* const* d_in, const int* in_sizes, int n_in,
                              void* d_out, int out_size, void* d_ws, size_t ws_size,
                              hipStream_t stream) {
  const float* H  = (const float*)d_in[0];
  const float* Aj = (const float*)d_in[1];
  const float* Wq = (const float*)d_in[2];
  const float* Wk = (const float*)d_in[3];
  const float* Wv = (const float*)d_in[4];
  float* out = (float*)d_out;
  const int NN = 8192, DD = 512;

  char* ws = (char*)d_ws;
  size_t off = 0;
  auto alloc = [&](size_t bytes) -> void* {
    void* p = ws + off;
    off += (bytes + 255) & ~(size_t)255;
    return p;
  };
  u16* Pbuf  = (u16*)alloc((size_t)NN * NN * 2);           // 128 MB
  u16* Hhi   = (u16*)alloc((size_t)NN * DD * 2);
  u16* Hlo   = (u16*)alloc((size_t)NN * DD * 2);
  u16* WThi  = (u16*)alloc((size_t)3 * DD * DD * 2);
  u16* WTlo  = (u16*)alloc((size_t)3 * DD * DD * 2);
  u16* PRhi  = (u16*)alloc((size_t)3 * NN * DD * 2);       // [HQ|HK|HV] hi
  u16* PRlo  = (u16*)alloc((size_t)3 * NN * DD * 2);
  u16* HVthi = (u16*)alloc((size_t)NN * DD * 2);
  float* mC  = (float*)alloc((size_t)64 * NN * 4);
  float* lC  = (float*)alloc((size_t)64 * NN * 4);
  float* Ft  = (float*)alloc((size_t)64 * NN * 4);
  char* Qh8  = (char*)alloc((size_t)NN * DD);
  char* Ql8  = (char*)alloc((size_t)NN * DD);
  char* Kh8  = (char*)alloc((size_t)NN * DD);
  char* Kl8  = (char*)alloc((size_t)NN * DD);
  float* sQ  = (float*)alloc((size_t)NN * 4);
  float* sK  = (float*)alloc((size_t)NN * 4);
  if (off > ws_size) return;  // workspace too small -> visible failure

  u16* HQhi = PRhi;                 u16* HQlo = PRlo;
  u16* HKhi = PRhi + (size_t)NN*DD; u16* HKlo = PRlo + (size_t)NN*DD;
  u16* HVhi = PRhi + (size_t)2*NN*DD;

  // K-split partials for PV: alias the dead region (Hhi..PRlo dead by then)
  float* part1 = (float*)Hhi;                              // 3 x 16.78 MB
  float* part2 = part1 + (size_t)NN * DD;
  float* part3 = part2 + (size_t)NN * DD;

  const float scl = 1.0f / sqrtf((float)DD);

  k_split<<<4096, 256, 0, stream>>>(H, Hhi, Hlo, NN * DD / 4);
  k_prepW<<<3072, 256, 0, stream>>>(Wq, Wk, Wv, WThi, WTlo);

  // fused Q/K/V projections: grid y = {w}*4 + {n-tile}
  dim3 gP(64, 12);
  gemm_bt<<<gP, 256, 0, stream>>>(Hhi, Hlo, WThi, WTlo, NN, DD, DD, PRhi, PRlo);

  dim3 gT(128, 8);
  k_transpose<<<gT, 256, 0, stream>>>(HVhi, HVthi, NN, DD);

  k_quant<<<2048, 256, 0, stream>>>(HQhi, HQlo, Qh8, Ql8, sQ);
  k_quant<<<2048, 256, 0, stream>>>(HKhi, HKlo, Kh8, Kl8, sK);

  // scores: i8 MFMA, 128(kv) x 64(q) tiles; chunk = 128 kv (NC = 64 unchanged)
  dim3 gS(64, 128);
  k_iscore<<<gS, 256, 0, stream>>>(Kh8, Kl8, Qh8, Ql8, sK, sQ,
                                   Aj, mC, lC, Pbuf, scl);

  k_reduce<<<32, 256, 0, stream>>>(mC, lC, Ft, NN, 64);

  // PV: out = (P'*F) @ HVt^T, 1-pass, 256x128 tiles, K split 4-way
  dim3 gO(32, 4, 4);
  k_big<3, 1, 4><<<gO, 256, 0, stream>>>(Pbuf, nullptr, HVthi, nullptr, NN, DD, NN,
                                         out, part1, part2, part3, Ft);

  k_sumout3<<<4096, 256, 0, stream>>>(out, part1, part2, part3, NN * DD / 4);
}